// Round 1
// 5390.445 us; speedup vs baseline: 1.4964x; 1.4964x over previous
//
#include <hip/hip_runtime.h>

// Shapes: VOCAB=128, EMBED=512, HIDDEN=1024, B=64, T=512. Inputs fp32, x int32.
// ws layout (bytes):
//   tableV : [128 vocab][4096 C] fp16   @ 0         (1 MB)  xin0+bias
//   fcwT   : [1024 k][128 v] fp16       @ 1048576   (256 KB)
//   bar    : [512 words] u32            @ 1310720   (2 KB)  monotonic barrier
//   hseq   : [514 buf][64 b][2048 k]f16 @ 1376256   (128.5 MB) fresh h per step
//   total ~136.2 MB (previous version used 66 MB of ws).
//
// FRESH-BUFFER h EXCHANGE (this round's change): step it reads buffer it,
// writes buffer it+1. A consumer XCD never touched buffer it+1 before step
// it+1, so its L2 cannot hold a stale line -> h loads are PLAIN CACHED
// dwordx4 loads (first block on an XCD misses to L3, the other 31 hit L2).
// Stores remain agent-scope relaxed atomics (write-through to the L3
// coherence point) + s_waitcnt vmcnt(0) before the barrier, as before.
// Line-ownership: cg = (blk&7)*16 + t  ==> every 128-B line of h is written
// only by blocks of ONE XCD (blk%8 == XCD round-robin), so a write-through
// that allocates in the producer's L2 stays coherent with all writers.
// buffer[t+2][b][1024+u] IS h2[t] -> FC reads hseq, h2s store dropped.
//
// Block (256 = 2 m x 128 cg): M-half m (rows m*32..+32), col-group cg
// (units cg*8..+8 of BOTH layers). Combined col C = cg*32 + cb*16 + g*4 + j
// <-> gate-row g*1024 + cg*8 + cb*4 + j.
// Wave w (12/block): layer = w<4 ? 0 : 1, K-chunk kc = w<4 ? w : w-4 (256
// halfs); covers both 16-col blocks cb=0,1 (B in REGISTERS, 64 VGPR/wave;
// A loaded once, used twice). C-tiles -> LDS -> cross-wave K-reduction by
// owner threads (waves 0-3: layer0 cells, 4-7: layer1 cells).
//
// Barrier = monotonic fire-and-forget adds + leader polls, zero cache ops.
// bar words (64-B spaced): grp[g]@g*16, root@128, rel[g]@144+g*16.

typedef _Float16 v8h __attribute__((ext_vector_type(8)));
typedef float v4f __attribute__((ext_vector_type(4)));
typedef _Float16 h2v __attribute__((ext_vector_type(2)));
typedef unsigned long long u64t;

__device__ __forceinline__ float sigf(float x) {
  return 1.0f / (1.0f + __expf(-x));
}

// ---------------------------------------------------------------- prep ----
__global__ __launch_bounds__(256) void prep_kernel(
    const float* __restrict__ emb, const float* __restrict__ w_ih0,
    const float* __restrict__ b_ih0, const float* __restrict__ b_hh0,
    const float* __restrict__ fc_w, _Float16* __restrict__ tableV,
    _Float16* __restrict__ fcwT, unsigned* __restrict__ zbuf,
    unsigned* __restrict__ bar) {
  const int blk = blockIdx.x, tid = threadIdx.x;
  if (blk < 2048) {
    // tableV[v][C] = emb[v]·w_ih0[row(C)] + b_ih0[row] + b_hh0[row]
    const int C = blk * 2 + (tid >> 7);
    const int v = tid & 127;
    const int row =
        ((C >> 2) & 3) * 1024 + (C >> 5) * 8 + ((C >> 4) & 1) * 4 + (C & 3);
    float acc = b_ih0[row] + b_hh0[row];
    const float* er = emb + v * 512;
    const float* wr = w_ih0 + row * 512;
#pragma unroll 4
    for (int k = 0; k < 512; ++k) acc = fmaf(er[k], wr[k], acc);
    tableV[v * 4096 + C] = (_Float16)acc;
  } else if (blk < 2560) {
    const int idx = (blk - 2048) * 256 + tid;   // [0, 131072)
    const int v = idx & 127, k = idx >> 7;
    fcwT[k * 128 + v] = (_Float16)fc_w[v * 1024 + k];
  } else if (blk < 2592) {
    // zero hseq buffers 0 and 1 (step-0/1 initial h state): 131072 dwords
    const int idx = (blk - 2560) * 256 + tid;
#pragma unroll
    for (int q = 0; q < 16; ++q) zbuf[idx * 16 + q] = 0u;
  } else {
    for (int i = tid; i < 512; i += 256) bar[i] = 0u;
  }
}

// ------------------------------------------------------------ recurrent ----
__global__ __launch_bounds__(768, 1) void lstm_mfma(
    const int* __restrict__ x, const _Float16* __restrict__ tableV,
    const float* __restrict__ w_hh0, const float* __restrict__ w_ih1,
    const float* __restrict__ w_hh1, const float* __restrict__ b_ih1,
    const float* __restrict__ b_hh1, _Float16* __restrict__ hseq,
    unsigned* __restrict__ bar) {
  __shared__ float zs[12 * 2 * 32 * 17];   // [wave][cb][row32][col16+1] 52 KB

  const int tid = threadIdx.x, blk = blockIdx.x;
  const int w = tid >> 6, l = tid & 63;
  const int lane16 = l & 15, quad = l >> 4;
  // XCD-local cg grouping: all 8 writer-blocks of any 128-B h line share
  // blk&7 (== XCD under the %8 round-robin dispatch).
  const int xcd = blk & 7, bidx = blk >> 3;
  const int m = bidx >> 4, cg = xcd * 16 + (bidx & 15);
  const int kc = (w < 4) ? w : (w - 4);

  // --- stage B-fragments into REGISTERS (once) ---
  // lane16 = local col c: gate g = c>>2, unit j = c&3; per cb: 8 kk x v8h.
  v8h breg0[8], breg1[8];
  {
    const int g = lane16 >> 2, j = lane16 & 3;
    const float* Wsrc;
    int kbase;
    if (w < 4) {
      Wsrc = w_hh0;
      kbase = kc * 256;
    } else {
      const int kcomb = kc * 256;
      if (kcomb < 1024) {
        Wsrc = w_ih1;
        kbase = kcomb;
      } else {
        Wsrc = w_hh1;
        kbase = kcomb - 1024;
      }
    }
#pragma unroll
    for (int cb = 0; cb < 2; ++cb) {
      const int row = g * 1024 + cg * 8 + cb * 4 + j;
      const float* rp = Wsrc + row * 1024 + kbase + quad * 8;
#pragma unroll
      for (int kk = 0; kk < 8; ++kk) {
        const float4 f0 = *(const float4*)(rp + kk * 32);
        const float4 f1 = *(const float4*)(rp + kk * 32 + 4);
        v8h b;
        b[0] = (_Float16)f0.x; b[1] = (_Float16)f0.y;
        b[2] = (_Float16)f0.z; b[3] = (_Float16)f0.w;
        b[4] = (_Float16)f1.x; b[5] = (_Float16)f1.y;
        b[6] = (_Float16)f1.z; b[7] = (_Float16)f1.w;
        if (cb == 0) breg0[kk] = b; else breg1[kk] = b;
      }
    }
  }

  // --- elementwise-owner constants ---
  // waves 0-3: layer0 cells; waves 4-7: layer1 cells.
  // lane: j = l&7 (unit within cg's 8), b_loc = (w&3)*8 + (l>>3).
  const int oj = l & 7, ojj = l & 3, ocb = (l >> 2) & 1;
  const int ob = (w & 3) * 8 + (l >> 3);
  const int obg = m * 32 + ob;
  float bias[4] = {0.f, 0.f, 0.f, 0.f};
  if (w >= 4 && w < 8) {
#pragma unroll
    for (int g = 0; g < 4; ++g) {
      const int row = g * 1024 + cg * 8 + ocb * 4 + ojj;
      bias[g] = b_ih1[row] + b_hh1[row];
    }
  }
  _Float16 tvh[4] = {0, 0, 0, 0};
  if (w < 4) {
    const int xv = x[obg * 512];
#pragma unroll
    for (int g = 0; g < 4; ++g)
      tvh[g] = tableV[xv * 4096 + cg * 32 + ocb * 16 + g * 4 + ojj];
  }

  float cst = 0.0f;
  const int gq = blk & 7;   // barrier group

  for (int it = 0; it <= 512; ++it) {
    const _Float16* hr = hseq + (size_t)it * 131072;       // fresh buffers
    _Float16* hw = hseq + (size_t)(it + 1) * 131072;

    v4f a00 = {0, 0, 0, 0}, a01 = {0, 0, 0, 0};
    v4f a10 = {0, 0, 0, 0}, a11 = {0, 0, 0, 0};
    const bool active = (w < 4) ? (it < 512) : (it >= 1);
    if (active) {
      // A: rows m*32 + mt*16 + lane16, halfs kc*256 + kk*32 + quad*8
      // PLAIN CACHED loads: buffer `it` address is fresh for this XCD's L2
      // (or holds only same-XCD write-through lines) -> always coherent.
      const _Float16* a0p = hr + (m * 32 + lane16) * 2048 + kc * 256 + quad * 8;
      const _Float16* a1p = a0p + 16 * 2048;
      v8h A0[8], A1[8];
#pragma unroll
      for (int kk = 0; kk < 8; ++kk) A0[kk] = *(const v8h*)(a0p + kk * 32);
#pragma unroll
      for (int kk = 0; kk < 8; ++kk) A1[kk] = *(const v8h*)(a1p + kk * 32);
#pragma unroll
      for (int kk = 0; kk < 8; ++kk) {
        a00 = __builtin_amdgcn_mfma_f32_16x16x32_f16(A0[kk], breg0[kk], a00, 0, 0, 0);
        a10 = __builtin_amdgcn_mfma_f32_16x16x32_f16(A0[kk], breg1[kk], a10, 0, 0, 0);
      }
#pragma unroll
      for (int kk = 0; kk < 8; ++kk) {
        a01 = __builtin_amdgcn_mfma_f32_16x16x32_f16(A1[kk], breg0[kk], a01, 0, 0, 0);
        a11 = __builtin_amdgcn_mfma_f32_16x16x32_f16(A1[kk], breg1[kk], a11, 0, 0, 0);
      }
    }

    // C-tiles -> LDS (C layout: row = quad*4+r, col = lane16)
#pragma unroll
    for (int r = 0; r < 4; ++r) {
      const int rw0 = quad * 4 + r, rw1 = 16 + quad * 4 + r;
      zs[((w * 2 + 0) * 32 + rw0) * 17 + lane16] = a00[r];
      zs[((w * 2 + 0) * 32 + rw1) * 17 + lane16] = a01[r];
      zs[((w * 2 + 1) * 32 + rw0) * 17 + lane16] = a10[r];
      zs[((w * 2 + 1) * 32 + rw1) * 17 + lane16] = a11[r];
    }
    __syncthreads();

    // owner reduction + cell update
    const bool do0 = (w < 4) && (it < 512);
    const bool do1 = (w >= 4 && w < 8) && (it >= 1);
    if (do0 || do1) {
      float z[4];
      if (do0) {
#pragma unroll
        for (int g = 0; g < 4; ++g) {
          float s = (float)tvh[g];
#pragma unroll
          for (int wv = 0; wv < 4; ++wv)
            s += zs[((wv * 2 + ocb) * 32 + ob) * 17 + g * 4 + ojj];
          z[g] = s;
        }
      } else {
#pragma unroll
        for (int g = 0; g < 4; ++g) {
          float s = bias[g];
#pragma unroll
          for (int wv = 4; wv < 12; ++wv)
            s += zs[((wv * 2 + ocb) * 32 + ob) * 17 + g * 4 + ojj];
          z[g] = s;
        }
      }
      const float ig = sigf(z[0]), fg = sigf(z[1]);
      const float gg = tanhf(z[2]), og = sigf(z[3]);
      cst = fg * cst + ig * gg;
      const float hv = og * tanhf(cst);

      // pack 8 unit-lanes (same b) -> two 8-B stores (lanes oj==0, oj==4)
      const unsigned hu =
          (unsigned)__builtin_bit_cast(unsigned short, (_Float16)hv);
      const unsigned p1 = (unsigned)__shfl_xor((int)hu, 1, 64);
      const unsigned lo = (oj & 1) ? ((p1 & 0xffffu) | (hu << 16))
                                   : ((hu & 0xffffu) | (p1 << 16));
      const unsigned p2 = (unsigned)__shfl_xor((int)lo, 2, 64);
      if ((oj & 3) == 0) {
        const u64t val = (u64t)lo | ((u64t)p2 << 32);
        if (do0) {
          __hip_atomic_store((u64t*)(hw + obg * 2048 + cg * 8 + oj), val,
                             __ATOMIC_RELAXED, __HIP_MEMORY_SCOPE_AGENT);
        } else {
          __hip_atomic_store((u64t*)(hw + obg * 2048 + 1024 + cg * 8 + oj),
                             val, __ATOMIC_RELAXED, __HIP_MEMORY_SCOPE_AGENT);
        }
      }
    }

    // prefetch next step's xin0 gather (tableV constant, L1-hot: no invs)
    if (w < 4 && it + 1 < 512) {
      const int xv = x[obg * 512 + it + 1];
#pragma unroll
      for (int g = 0; g < 4; ++g)
        tvh[g] = tableV[xv * 4096 + cg * 32 + ocb * 16 + g * 4 + ojj];
    }

    if (it < 512) {
      // ---- pure-atomic monotonic barrier (NO cache maintenance) ----
      asm volatile("s_waitcnt vmcnt(0)" ::: "memory");  // h stores at L3
      __syncthreads();
      if (tid == 0) {
        atomicAdd(&bar[gq * 16], 1u);                   // fire-and-forget
        if (blk == gq) {                                // group leader
          while (__hip_atomic_load(&bar[gq * 16], __ATOMIC_RELAXED,
                                   __HIP_MEMORY_SCOPE_AGENT) <
                 32u * (unsigned)(it + 1))
            __builtin_amdgcn_s_sleep(1);
          atomicAdd(&bar[128], 1u);
          if (blk == 0) {                               // root
            while (__hip_atomic_load(&bar[128], __ATOMIC_RELAXED,
                                     __HIP_MEMORY_SCOPE_AGENT) <
                   8u * (unsigned)(it + 1))
              __builtin_amdgcn_s_sleep(1);
#pragma unroll
            for (int xx = 0; xx < 8; ++xx)
              __hip_atomic_store(&bar[144 + xx * 16], (unsigned)(it + 1),
                                 __ATOMIC_RELAXED, __HIP_MEMORY_SCOPE_AGENT);
          }
        }
        while (__hip_atomic_load(&bar[144 + gq * 16], __ATOMIC_RELAXED,
                                 __HIP_MEMORY_SCOPE_AGENT) <
               (unsigned)(it + 1))
          __builtin_amdgcn_s_sleep(1);
      }
      __syncthreads();
      // keep the fresh-buffer plain loads from being hoisted above release
      asm volatile("" ::: "memory");
    }
  }
}

// ---------------------------------------------------------------- FC ----
__global__ __launch_bounds__(256, 2) void fc_kernel(
    const _Float16* __restrict__ hseq, const _Float16* __restrict__ fcwT,
    const float* __restrict__ fc_b, float* __restrict__ out) {
  __shared__ float hl[16][1024];      // 64 KB
  const int tid = threadIdx.x;
  const int t = blockIdx.x >> 2, bs = blockIdx.x & 3;
  const int v = tid & 127, hh = tid >> 7;

  // h2[t][b][u] lives at hseq buffer t+2, row b, halfs 1024..2047
  const h2v* hp = (const h2v*)hseq;
  const size_t base = (size_t)(t + 2) * 65536 + 512;
  for (int idx = tid; idx < 8192; idx += 256) {
    const int bl = idx >> 9, kp = idx & 511;
    const h2v pr = hp[base + (size_t)((bs * 16 + bl)) * 1024 + kp];
    hl[bl][2 * kp] = (float)pr.x;
    hl[bl][2 * kp + 1] = (float)pr.y;
  }
  __syncthreads();

  float acc[8];
#pragma unroll
  for (int i = 0; i < 8; ++i) acc[i] = 0.0f;
  const int bl0 = hh * 8;
#pragma unroll 1
  for (int k4 = 0; k4 < 256; ++k4) {
    const int k = k4 * 4;
    const float w0 = (float)fcwT[(k + 0) * 128 + v];
    const float w1 = (float)fcwT[(k + 1) * 128 + v];
    const float w2 = (float)fcwT[(k + 2) * 128 + v];
    const float w3 = (float)fcwT[(k + 3) * 128 + v];
#pragma unroll
    for (int i = 0; i < 8; ++i) {
      const float4 hv = *(const float4*)&hl[bl0 + i][k];
      acc[i] += hv.x * w0 + hv.y * w1 + hv.z * w2 + hv.w * w3;
    }
  }
  const float bias = fc_b[v];
#pragma unroll
  for (int i = 0; i < 8; ++i) {
    const int bb = bs * 16 + bl0 + i;
    out[(bb * 512 + t) * 128 + v] = acc[i] + bias;
  }
}

// ------------------------------------------------------------- launch ----
extern "C" void kernel_launch(void* const* d_in, const int* in_sizes, int n_in,
                              void* d_out, int out_size, void* d_ws,
                              size_t ws_size, hipStream_t stream) {
  const int* x = (const int*)d_in[0];
  const float* emb = (const float*)d_in[1];
  const float* w_ih0 = (const float*)d_in[2];
  const float* w_hh0 = (const float*)d_in[3];
  const float* b_ih0 = (const float*)d_in[4];
  const float* b_hh0 = (const float*)d_in[5];
  const float* w_ih1 = (const float*)d_in[6];
  const float* w_hh1 = (const float*)d_in[7];
  const float* b_ih1 = (const float*)d_in[8];
  const float* b_hh1 = (const float*)d_in[9];
  const float* fc_w = (const float*)d_in[10];
  const float* fc_b = (const float*)d_in[11];
  float* out = (float*)d_out;

  char* ws = (char*)d_ws;
  _Float16* tableV = (_Float16*)(ws);
  _Float16* fcwT = (_Float16*)(ws + 1048576);
  unsigned* bar = (unsigned*)(ws + 1310720);
  _Float16* hseq = (_Float16*)(ws + 1376256);   // 514 x 262144 B
  unsigned* zb = (unsigned*)(ws + 1376256);     // zero buffers 0,1

  prep_kernel<<<2593, 256, 0, stream>>>(emb, w_ih0, b_ih0, b_hh0, fc_w,
                                        tableV, fcwT, zb, bar);

  const _Float16* tableVc = tableV;
  _Float16* hseqa = hseq;
  unsigned* bara = bar;
  void* args[] = {(void*)&x,     (void*)&tableVc, (void*)&w_hh0,
                  (void*)&w_ih1, (void*)&w_hh1,   (void*)&b_ih1,
                  (void*)&b_hh1, (void*)&hseqa,   (void*)&bara};
  hipLaunchCooperativeKernel(lstm_mfma, dim3(256), dim3(768), args, 0, stream);

  fc_kernel<<<2048, 256, 0, stream>>>(hseq, fcwT, fc_b, out);
}

// Round 2
// 5071.767 us; speedup vs baseline: 1.5904x; 1.0628x over previous
//
#include <hip/hip_runtime.h>

// Shapes: VOCAB=128, EMBED=512, HIDDEN=1024, B=64, T=512. Inputs fp32, x int32.
// ws layout (bytes):
//   tableV : [128 vocab][4096 C] fp16   @ 0         (1 MB)  xin0+bias
//   fcwT   : [1024 k][128 v] fp16       @ 1048576   (256 KB)
//   bar    : [512 words] u32            @ 1310720   (2 KB)  flat barrier
//   hseq   : [514 buf][64 b][2048 k]f16 @ 1376256   (128.5 MB) fresh h per step
//
// FRESH-BUFFER h EXCHANGE (R1, kept): step it reads buffer it, writes buffer
// it+1. A consumer XCD never touched buffer it+1 before step it+1, so its L2
// cannot hold a stale line -> h loads are PLAIN CACHED dwordx4 loads (first
// block on an XCD misses to L3, the other 31 hit L2). Stores remain
// agent-scope relaxed atomics (write-through to the L3 coherence point) +
// s_waitcnt vmcnt(0) before the barrier. Line-ownership: cg = (blk&7)*16+t
// ==> every 128-B h line is written only by blocks of ONE XCD.
// buffer[t+2][b][1024+u] IS h2[t] -> FC reads hseq directly.
//
// FLAT m-SPLIT BARRIER (this round): block (m,cg) only ever reads h rows of
// its own m-half (A rows = m*32+..., both layers; x/tableV gathers are own
// rows; weights per-block in regs). The two m-halves are fully independent
// 128-block recurrences -> two independent SINGLE-STAGE barriers. Arrival:
// atomicAdd to word (m*8 + blk&7) (16 blocks/word, kills add serialization).
// Wait: tid0 polls all 8 words of its m (8 independent relaxed loads
// pipelined ~= one L3 latency) until min >= 16*(it+1). This removes the
// group-leader and root poll stages (~2 L3 round-trips/step) of the old
// 3-level barrier. bar words 64-B spaced: word(m,g) @ (m*8+g)*16.
//
// Block (256 = 2 m x 128 cg): M-half m (rows m*32..+32), col-group cg
// (units cg*8..+8 of BOTH layers). Combined col C = cg*32 + cb*16 + g*4 + j
// <-> gate-row g*1024 + cg*8 + cb*4 + j.
// Wave w (12/block): layer = w<4 ? 0 : 1, K-chunk kc = w<4 ? w : w-4 (256
// halfs); covers both 16-col blocks cb=0,1 (B in REGISTERS, 64 VGPR/wave;
// A loaded once, used twice). C-tiles -> LDS -> cross-wave K-reduction by
// owner threads (waves 0-3: layer0 cells, 4-7: layer1 cells).

typedef _Float16 v8h __attribute__((ext_vector_type(8)));
typedef float v4f __attribute__((ext_vector_type(4)));
typedef _Float16 h2v __attribute__((ext_vector_type(2)));
typedef unsigned long long u64t;

__device__ __forceinline__ float sigf(float x) {
  return 1.0f / (1.0f + __expf(-x));
}

// ---------------------------------------------------------------- prep ----
__global__ __launch_bounds__(256) void prep_kernel(
    const float* __restrict__ emb, const float* __restrict__ w_ih0,
    const float* __restrict__ b_ih0, const float* __restrict__ b_hh0,
    const float* __restrict__ fc_w, _Float16* __restrict__ tableV,
    _Float16* __restrict__ fcwT, unsigned* __restrict__ zbuf,
    unsigned* __restrict__ bar) {
  const int blk = blockIdx.x, tid = threadIdx.x;
  if (blk < 2048) {
    // tableV[v][C] = emb[v]·w_ih0[row(C)] + b_ih0[row] + b_hh0[row]
    const int C = blk * 2 + (tid >> 7);
    const int v = tid & 127;
    const int row =
        ((C >> 2) & 3) * 1024 + (C >> 5) * 8 + ((C >> 4) & 1) * 4 + (C & 3);
    float acc = b_ih0[row] + b_hh0[row];
    const float* er = emb + v * 512;
    const float* wr = w_ih0 + row * 512;
#pragma unroll 4
    for (int k = 0; k < 512; ++k) acc = fmaf(er[k], wr[k], acc);
    tableV[v * 4096 + C] = (_Float16)acc;
  } else if (blk < 2560) {
    const int idx = (blk - 2048) * 256 + tid;   // [0, 131072)
    const int v = idx & 127, k = idx >> 7;
    fcwT[k * 128 + v] = (_Float16)fc_w[v * 1024 + k];
  } else if (blk < 2592) {
    // zero hseq buffers 0 and 1 (step-0/1 initial h state): 131072 dwords
    const int idx = (blk - 2560) * 256 + tid;
#pragma unroll
    for (int q = 0; q < 16; ++q) zbuf[idx * 16 + q] = 0u;
  } else {
    for (int i = tid; i < 512; i += 256) bar[i] = 0u;
  }
}

// ------------------------------------------------------------ recurrent ----
__global__ __launch_bounds__(768, 1) void lstm_mfma(
    const int* __restrict__ x, const _Float16* __restrict__ tableV,
    const float* __restrict__ w_hh0, const float* __restrict__ w_ih1,
    const float* __restrict__ w_hh1, const float* __restrict__ b_ih1,
    const float* __restrict__ b_hh1, _Float16* __restrict__ hseq,
    unsigned* __restrict__ bar) {
  __shared__ float zs[12 * 2 * 32 * 17];   // [wave][cb][row32][col16+1] 52 KB

  const int tid = threadIdx.x, blk = blockIdx.x;
  const int w = tid >> 6, l = tid & 63;
  const int lane16 = l & 15, quad = l >> 4;
  // XCD-local cg grouping: all 8 writer-blocks of any 128-B h line share
  // blk&7 (== XCD under the %8 round-robin dispatch).
  const int xcd = blk & 7, bidx = blk >> 3;
  const int m = bidx >> 4, cg = xcd * 16 + (bidx & 15);
  const int kc = (w < 4) ? w : (w - 4);

  // --- stage B-fragments into REGISTERS (once) ---
  // lane16 = local col c: gate g = c>>2, unit j = c&3; per cb: 8 kk x v8h.
  v8h breg0[8], breg1[8];
  {
    const int g = lane16 >> 2, j = lane16 & 3;
    const float* Wsrc;
    int kbase;
    if (w < 4) {
      Wsrc = w_hh0;
      kbase = kc * 256;
    } else {
      const int kcomb = kc * 256;
      if (kcomb < 1024) {
        Wsrc = w_ih1;
        kbase = kcomb;
      } else {
        Wsrc = w_hh1;
        kbase = kcomb - 1024;
      }
    }
#pragma unroll
    for (int cb = 0; cb < 2; ++cb) {
      const int row = g * 1024 + cg * 8 + cb * 4 + j;
      const float* rp = Wsrc + row * 1024 + kbase + quad * 8;
#pragma unroll
      for (int kk = 0; kk < 8; ++kk) {
        const float4 f0 = *(const float4*)(rp + kk * 32);
        const float4 f1 = *(const float4*)(rp + kk * 32 + 4);
        v8h b;
        b[0] = (_Float16)f0.x; b[1] = (_Float16)f0.y;
        b[2] = (_Float16)f0.z; b[3] = (_Float16)f0.w;
        b[4] = (_Float16)f1.x; b[5] = (_Float16)f1.y;
        b[6] = (_Float16)f1.z; b[7] = (_Float16)f1.w;
        if (cb == 0) breg0[kk] = b; else breg1[kk] = b;
      }
    }
  }

  // --- elementwise-owner constants ---
  // waves 0-3: layer0 cells; waves 4-7: layer1 cells.
  // lane: j = l&7 (unit within cg's 8), b_loc = (w&3)*8 + (l>>3).
  const int oj = l & 7, ojj = l & 3, ocb = (l >> 2) & 1;
  const int ob = (w & 3) * 8 + (l >> 3);
  const int obg = m * 32 + ob;
  float bias[4] = {0.f, 0.f, 0.f, 0.f};
  if (w >= 4 && w < 8) {
#pragma unroll
    for (int g = 0; g < 4; ++g) {
      const int row = g * 1024 + cg * 8 + ocb * 4 + ojj;
      bias[g] = b_ih1[row] + b_hh1[row];
    }
  }
  _Float16 tvh[4] = {0, 0, 0, 0};
  if (w < 4) {
    const int xv = x[obg * 512];
#pragma unroll
    for (int g = 0; g < 4; ++g)
      tvh[g] = tableV[xv * 4096 + cg * 32 + ocb * 16 + g * 4 + ojj];
  }

  float cst = 0.0f;
  const int gq = blk & 7;   // arrival word within this m-half

  for (int it = 0; it <= 512; ++it) {
    const _Float16* hr = hseq + (size_t)it * 131072;       // fresh buffers
    _Float16* hw = hseq + (size_t)(it + 1) * 131072;

    v4f a00 = {0, 0, 0, 0}, a01 = {0, 0, 0, 0};
    v4f a10 = {0, 0, 0, 0}, a11 = {0, 0, 0, 0};
    const bool active = (w < 4) ? (it < 512) : (it >= 1);
    if (active) {
      // A: rows m*32 + mt*16 + lane16, halfs kc*256 + kk*32 + quad*8
      // PLAIN CACHED loads: buffer `it` address is fresh for this XCD's L2
      // (or holds only same-XCD write-through lines) -> always coherent.
      const _Float16* a0p = hr + (m * 32 + lane16) * 2048 + kc * 256 + quad * 8;
      const _Float16* a1p = a0p + 16 * 2048;
      v8h A0[8], A1[8];
#pragma unroll
      for (int kk = 0; kk < 8; ++kk) A0[kk] = *(const v8h*)(a0p + kk * 32);
#pragma unroll
      for (int kk = 0; kk < 8; ++kk) A1[kk] = *(const v8h*)(a1p + kk * 32);
#pragma unroll
      for (int kk = 0; kk < 8; ++kk) {
        a00 = __builtin_amdgcn_mfma_f32_16x16x32_f16(A0[kk], breg0[kk], a00, 0, 0, 0);
        a10 = __builtin_amdgcn_mfma_f32_16x16x32_f16(A0[kk], breg1[kk], a10, 0, 0, 0);
      }
#pragma unroll
      for (int kk = 0; kk < 8; ++kk) {
        a01 = __builtin_amdgcn_mfma_f32_16x16x32_f16(A1[kk], breg0[kk], a01, 0, 0, 0);
        a11 = __builtin_amdgcn_mfma_f32_16x16x32_f16(A1[kk], breg1[kk], a11, 0, 0, 0);
      }
    }

    // C-tiles -> LDS (C layout: row = quad*4+r, col = lane16)
#pragma unroll
    for (int r = 0; r < 4; ++r) {
      const int rw0 = quad * 4 + r, rw1 = 16 + quad * 4 + r;
      zs[((w * 2 + 0) * 32 + rw0) * 17 + lane16] = a00[r];
      zs[((w * 2 + 0) * 32 + rw1) * 17 + lane16] = a01[r];
      zs[((w * 2 + 1) * 32 + rw0) * 17 + lane16] = a10[r];
      zs[((w * 2 + 1) * 32 + rw1) * 17 + lane16] = a11[r];
    }
    __syncthreads();

    // owner reduction + cell update
    const bool do0 = (w < 4) && (it < 512);
    const bool do1 = (w >= 4 && w < 8) && (it >= 1);
    if (do0 || do1) {
      float z[4];
      if (do0) {
#pragma unroll
        for (int g = 0; g < 4; ++g) {
          float s = (float)tvh[g];
#pragma unroll
          for (int wv = 0; wv < 4; ++wv)
            s += zs[((wv * 2 + ocb) * 32 + ob) * 17 + g * 4 + ojj];
          z[g] = s;
        }
      } else {
#pragma unroll
        for (int g = 0; g < 4; ++g) {
          float s = bias[g];
#pragma unroll
          for (int wv = 4; wv < 12; ++wv)
            s += zs[((wv * 2 + ocb) * 32 + ob) * 17 + g * 4 + ojj];
          z[g] = s;
        }
      }
      const float ig = sigf(z[0]), fg = sigf(z[1]);
      const float gg = tanhf(z[2]), og = sigf(z[3]);
      cst = fg * cst + ig * gg;
      const float hv = og * tanhf(cst);

      // pack 8 unit-lanes (same b) -> two 8-B stores (lanes oj==0, oj==4)
      const unsigned hu =
          (unsigned)__builtin_bit_cast(unsigned short, (_Float16)hv);
      const unsigned p1 = (unsigned)__shfl_xor((int)hu, 1, 64);
      const unsigned lo = (oj & 1) ? ((p1 & 0xffffu) | (hu << 16))
                                   : ((hu & 0xffffu) | (p1 << 16));
      const unsigned p2 = (unsigned)__shfl_xor((int)lo, 2, 64);
      if ((oj & 3) == 0) {
        const u64t val = (u64t)lo | ((u64t)p2 << 32);
        if (do0) {
          __hip_atomic_store((u64t*)(hw + obg * 2048 + cg * 8 + oj), val,
                             __ATOMIC_RELAXED, __HIP_MEMORY_SCOPE_AGENT);
        } else {
          __hip_atomic_store((u64t*)(hw + obg * 2048 + 1024 + cg * 8 + oj),
                             val, __ATOMIC_RELAXED, __HIP_MEMORY_SCOPE_AGENT);
        }
      }
    }

    // prefetch next step's xin0 gather (tableV constant, L1-hot: no invs)
    if (w < 4 && it + 1 < 512) {
      const int xv = x[obg * 512 + it + 1];
#pragma unroll
      for (int g = 0; g < 4; ++g)
        tvh[g] = tableV[xv * 4096 + cg * 32 + ocb * 16 + g * 4 + ojj];
    }

    if (it < 512) {
      // ---- flat m-split barrier: one add, one poll stage, no leaders ----
      asm volatile("s_waitcnt vmcnt(0)" ::: "memory");  // h stores at L3
      __syncthreads();
      if (tid == 0) {
        atomicAdd(&bar[(m * 8 + gq) * 16], 1u);         // fire-and-forget
        const unsigned tgt = 16u * (unsigned)(it + 1);
        for (;;) {
          unsigned v[8];
#pragma unroll
          for (int g = 0; g < 8; ++g)
            v[g] = __hip_atomic_load(&bar[(m * 8 + g) * 16], __ATOMIC_RELAXED,
                                     __HIP_MEMORY_SCOPE_AGENT);
          unsigned mn = v[0];
#pragma unroll
          for (int g = 1; g < 8; ++g) mn = (v[g] < mn) ? v[g] : mn;
          if (mn >= tgt) break;
          __builtin_amdgcn_s_sleep(1);
        }
      }
      __syncthreads();
      // keep the fresh-buffer plain loads from being hoisted above release
      asm volatile("" ::: "memory");
    }
  }
}

// ---------------------------------------------------------------- FC ----
__global__ __launch_bounds__(256, 2) void fc_kernel(
    const _Float16* __restrict__ hseq, const _Float16* __restrict__ fcwT,
    const float* __restrict__ fc_b, float* __restrict__ out) {
  __shared__ float hl[16][1024];      // 64 KB
  const int tid = threadIdx.x;
  const int t = blockIdx.x >> 2, bs = blockIdx.x & 3;
  const int v = tid & 127, hh = tid >> 7;

  // h2[t][b][u] lives at hseq buffer t+2, row b, halfs 1024..2047
  const h2v* hp = (const h2v*)hseq;
  const size_t base = (size_t)(t + 2) * 65536 + 512;
  for (int idx = tid; idx < 8192; idx += 256) {
    const int bl = idx >> 9, kp = idx & 511;
    const h2v pr = hp[base + (size_t)((bs * 16 + bl)) * 1024 + kp];
    hl[bl][2 * kp] = (float)pr.x;
    hl[bl][2 * kp + 1] = (float)pr.y;
  }
  __syncthreads();

  float acc[8];
#pragma unroll
  for (int i = 0; i < 8; ++i) acc[i] = 0.0f;
  const int bl0 = hh * 8;
#pragma unroll 1
  for (int k4 = 0; k4 < 256; ++k4) {
    const int k = k4 * 4;
    const float w0 = (float)fcwT[(k + 0) * 128 + v];
    const float w1 = (float)fcwT[(k + 1) * 128 + v];
    const float w2 = (float)fcwT[(k + 2) * 128 + v];
    const float w3 = (float)fcwT[(k + 3) * 128 + v];
#pragma unroll
    for (int i = 0; i < 8; ++i) {
      const float4 hv = *(const float4*)&hl[bl0 + i][k];
      acc[i] += hv.x * w0 + hv.y * w1 + hv.z * w2 + hv.w * w3;
    }
  }
  const float bias = fc_b[v];
#pragma unroll
  for (int i = 0; i < 8; ++i) {
    const int bb = bs * 16 + bl0 + i;
    out[(bb * 512 + t) * 128 + v] = acc[i] + bias;
  }
}

// ------------------------------------------------------------- launch ----
extern "C" void kernel_launch(void* const* d_in, const int* in_sizes, int n_in,
                              void* d_out, int out_size, void* d_ws,
                              size_t ws_size, hipStream_t stream) {
  const int* x = (const int*)d_in[0];
  const float* emb = (const float*)d_in[1];
  const float* w_ih0 = (const float*)d_in[2];
  const float* w_hh0 = (const float*)d_in[3];
  const float* b_ih0 = (const float*)d_in[4];
  const float* b_hh0 = (const float*)d_in[5];
  const float* w_ih1 = (const float*)d_in[6];
  const float* w_hh1 = (const float*)d_in[7];
  const float* b_ih1 = (const float*)d_in[8];
  const float* b_hh1 = (const float*)d_in[9];
  const float* fc_w = (const float*)d_in[10];
  const float* fc_b = (const float*)d_in[11];
  float* out = (float*)d_out;

  char* ws = (char*)d_ws;
  _Float16* tableV = (_Float16*)(ws);
  _Float16* fcwT = (_Float16*)(ws + 1048576);
  unsigned* bar = (unsigned*)(ws + 1310720);
  _Float16* hseq = (_Float16*)(ws + 1376256);   // 514 x 262144 B
  unsigned* zb = (unsigned*)(ws + 1376256);     // zero buffers 0,1

  prep_kernel<<<2593, 256, 0, stream>>>(emb, w_ih0, b_ih0, b_hh0, fc_w,
                                        tableV, fcwT, zb, bar);

  const _Float16* tableVc = tableV;
  _Float16* hseqa = hseq;
  unsigned* bara = bar;
  void* args[] = {(void*)&x,     (void*)&tableVc, (void*)&w_hh0,
                  (void*)&w_ih1, (void*)&w_hh1,   (void*)&b_ih1,
                  (void*)&b_hh1, (void*)&hseqa,   (void*)&bara};
  hipLaunchCooperativeKernel(lstm_mfma, dim3(256), dim3(768), args, 0, stream);

  fc_kernel<<<2048, 256, 0, stream>>>(hseq, fcwT, fc_b, out);
}

// Round 4
// 4879.783 us; speedup vs baseline: 1.6530x; 1.0393x over previous
//
#include <hip/hip_runtime.h>

// Shapes: VOCAB=128, EMBED=512, HIDDEN=1024, B=64, T=512. Inputs fp32, x int32.
// ws layout (bytes):
//   tableV : [128 vocab][4096 C] fp16   @ 0         (1 MB)  xin0+bias
//   fcwT   : [1024 k][128 v] fp16       @ 1048576   (256 KB)
//   bar    : [512 words] u32            @ 1310720   (2 KB)  flat barrier
//   hseq   : [514 buf][64 b][2048 k]f16 @ 1376256   (128.5 MB) fresh h per step
//
// FRESH-BUFFER h EXCHANGE (R1, kept): step it reads buffer it, writes buffer
// it+1. A consumer XCD never touched buffer it+1 before step it+1, so its L2
// cannot hold a stale line -> h loads are PLAIN CACHED dwordx4 loads. Stores
// remain agent-scope relaxed atomics (write-through to the L3 coherence
// point) + s_waitcnt vmcnt(0) before the barrier. Line-ownership:
// cg = (blk&7)*16+t ==> every 128-B h line is written only by ONE XCD.
// buffer[t+2][b][1024+u] IS h2[t] -> FC reads hseq directly.
//
// FLAT m-SPLIT BARRIER (R2, kept): two independent single-stage barriers
// (one per m-half); arrival adds spread over 8 words, tid0 polls min of 8.
//
// SWIZZLED LDS REDUCTION (this round, re-run after infra flake): old zs
// [w][cb][row32][17] had 4-way write conflicts (bank = (quad*4+lane16)%32)
// and 16-32 scalar owner reads = 2.01e8 conflict cycles/dispatch (~0.64
// us/step serial). New layout:
//   zs[w][r(=row&3)][rq(=row32>>2, 0..7)][col32]
//   col32 = (cb*16 + colp) ^ ((rq&1)<<4),  colp = j*4 + g  (lane16 = g*4+j)
// Writes: bank = colp ^ ((quad&1)<<4) -> even/odd quads split 16-bank halves
// = 2-way (free). Owner reads: one aligned float4 (b128) per source wave,
// gates g=0..3 contiguous; bank-starts span all 32 banks via (ocb,l>>5,ojj)
// -> minimum 8-phase b128, no excess conflict. Gate-sum becomes v4f adds.
// Transcendentals: only constructs proven on this harness in R0-R2
// (__expf + real division); tanh = 1 - 2/(e^{2x}+1), no libm tanhf.
//
// Block (256 = 2 m x 128 cg): M-half m (rows m*32..+32), col-group cg
// (units cg*8..+8 of BOTH layers). Combined col C = cg*32 + cb*16 + g*4 + j
// <-> gate-row g*1024 + cg*8 + cb*4 + j.
// Wave w (12/block): layer = w<4 ? 0 : 1, K-chunk kc = w<4 ? w : w-4 (256
// halfs); covers both 16-col blocks cb=0,1 (B in REGISTERS; A loaded once,
// used twice). C-tiles -> LDS -> cross-wave K-reduction by owner threads
// (waves 0-3: layer0 cells, 4-7: layer1 cells).

typedef _Float16 v8h __attribute__((ext_vector_type(8)));
typedef float v4f __attribute__((ext_vector_type(4)));
typedef _Float16 h2v __attribute__((ext_vector_type(2)));
typedef unsigned long long u64t;

__device__ __forceinline__ float sigf(float x) {
  return 1.0f / (1.0f + __expf(-x));
}
__device__ __forceinline__ float tanhfast(float x) {
  // tanh = 1 - 2/(e^{2x}+1); graceful at +-inf (__expf -> inf/0)
  return 1.0f - 2.0f / (1.0f + __expf(2.0f * x));
}

// ---------------------------------------------------------------- prep ----
__global__ __launch_bounds__(256) void prep_kernel(
    const float* __restrict__ emb, const float* __restrict__ w_ih0,
    const float* __restrict__ b_ih0, const float* __restrict__ b_hh0,
    const float* __restrict__ fc_w, _Float16* __restrict__ tableV,
    _Float16* __restrict__ fcwT, unsigned* __restrict__ zbuf,
    unsigned* __restrict__ bar) {
  const int blk = blockIdx.x, tid = threadIdx.x;
  if (blk < 2048) {
    // tableV[v][C] = emb[v]·w_ih0[row(C)] + b_ih0[row] + b_hh0[row]
    const int C = blk * 2 + (tid >> 7);
    const int v = tid & 127;
    const int row =
        ((C >> 2) & 3) * 1024 + (C >> 5) * 8 + ((C >> 4) & 1) * 4 + (C & 3);
    float acc = b_ih0[row] + b_hh0[row];
    const float* er = emb + v * 512;
    const float* wr = w_ih0 + row * 512;
#pragma unroll 4
    for (int k = 0; k < 512; ++k) acc = fmaf(er[k], wr[k], acc);
    tableV[v * 4096 + C] = (_Float16)acc;
  } else if (blk < 2560) {
    const int idx = (blk - 2048) * 256 + tid;   // [0, 131072)
    const int v = idx & 127, k = idx >> 7;
    fcwT[k * 128 + v] = (_Float16)fc_w[v * 1024 + k];
  } else if (blk < 2592) {
    // zero hseq buffers 0 and 1 (step-0/1 initial h state): 131072 dwords
    const int idx = (blk - 2560) * 256 + tid;
#pragma unroll
    for (int q = 0; q < 16; ++q) zbuf[idx * 16 + q] = 0u;
  } else {
    for (int i = tid; i < 512; i += 256) bar[i] = 0u;
  }
}

// ------------------------------------------------------------ recurrent ----
__global__ __launch_bounds__(768, 1) void lstm_mfma(
    const int* __restrict__ x, const _Float16* __restrict__ tableV,
    const float* __restrict__ w_hh0, const float* __restrict__ w_ih1,
    const float* __restrict__ w_hh1, const float* __restrict__ b_ih1,
    const float* __restrict__ b_hh1, _Float16* __restrict__ hseq,
    unsigned* __restrict__ bar) {
  // [wave12][r4][rq8][col32] floats, col32 = (cb*16+colp)^((rq&1)<<4): 48 KB
  __shared__ __align__(16) float zs[12 * 4 * 8 * 32];

  const int tid = threadIdx.x, blk = blockIdx.x;
  const int w = tid >> 6, l = tid & 63;
  const int lane16 = l & 15, quad = l >> 4;
  // XCD-local cg grouping: all 8 writer-blocks of any 128-B h line share
  // blk&7 (== XCD under the %8 round-robin dispatch).
  const int xcd = blk & 7, bidx = blk >> 3;
  const int m = bidx >> 4, cg = xcd * 16 + (bidx & 15);
  const int kc = (w < 4) ? w : (w - 4);

  // --- stage B-fragments into REGISTERS (once) ---
  // lane16 = local col c: gate g = c>>2, unit j = c&3; per cb: 8 kk x v8h.
  v8h breg0[8], breg1[8];
  {
    const int g = lane16 >> 2, j = lane16 & 3;
    const float* Wsrc;
    int kbase;
    if (w < 4) {
      Wsrc = w_hh0;
      kbase = kc * 256;
    } else {
      const int kcomb = kc * 256;
      if (kcomb < 1024) {
        Wsrc = w_ih1;
        kbase = kcomb;
      } else {
        Wsrc = w_hh1;
        kbase = kcomb - 1024;
      }
    }
#pragma unroll
    for (int cb = 0; cb < 2; ++cb) {
      const int row = g * 1024 + cg * 8 + cb * 4 + j;
      const float* rp = Wsrc + row * 1024 + kbase + quad * 8;
#pragma unroll
      for (int kk = 0; kk < 8; ++kk) {
        const float4 f0 = *(const float4*)(rp + kk * 32);
        const float4 f1 = *(const float4*)(rp + kk * 32 + 4);
        v8h b;
        b[0] = (_Float16)f0.x; b[1] = (_Float16)f0.y;
        b[2] = (_Float16)f0.z; b[3] = (_Float16)f0.w;
        b[4] = (_Float16)f1.x; b[5] = (_Float16)f1.y;
        b[6] = (_Float16)f1.z; b[7] = (_Float16)f1.w;
        if (cb == 0) breg0[kk] = b; else breg1[kk] = b;
      }
    }
  }

  // --- elementwise-owner constants ---
  // waves 0-3: layer0 cells; waves 4-7: layer1 cells.
  // lane: j = l&7 (unit within cg's 8), b_loc = (w&3)*8 + (l>>3).
  const int oj = l & 7, ojj = l & 3, ocb = (l >> 2) & 1;
  const int ob = (w & 3) * 8 + (l >> 3);
  const int obg = m * 32 + ob;
  // swizzle constants
  const int colp = (lane16 & 3) * 4 + (lane16 >> 2);      // j*4+g
  const int cswz = colp ^ ((quad & 1) << 4);              // write col, cb=0
  const int rr = ob & 3, rqo = ob >> 2;                   // owner row split
  const int rcol = (ocb * 16 + ojj * 4) ^ ((rqo & 1) << 4);  // owner read col

  v4f bias4 = {0.f, 0.f, 0.f, 0.f};
  if (w >= 4 && w < 8) {
#pragma unroll
    for (int g = 0; g < 4; ++g) {
      const int row = g * 1024 + cg * 8 + ocb * 4 + ojj;
      bias4[g] = b_ih1[row] + b_hh1[row];
    }
  }
  _Float16 tvh[4] = {0, 0, 0, 0};
  if (w < 4) {
    const int xv = x[obg * 512];
#pragma unroll
    for (int g = 0; g < 4; ++g)
      tvh[g] = tableV[xv * 4096 + cg * 32 + ocb * 16 + g * 4 + ojj];
  }

  float cst = 0.0f;
  const int gq = blk & 7;   // arrival word within this m-half

  for (int it = 0; it <= 512; ++it) {
    const _Float16* hr = hseq + (size_t)it * 131072;       // fresh buffers
    _Float16* hw = hseq + (size_t)(it + 1) * 131072;

    v4f a00 = {0, 0, 0, 0}, a01 = {0, 0, 0, 0};
    v4f a10 = {0, 0, 0, 0}, a11 = {0, 0, 0, 0};
    const bool active = (w < 4) ? (it < 512) : (it >= 1);
    if (active) {
      // A: rows m*32 + mt*16 + lane16, halfs kc*256 + kk*32 + quad*8
      // PLAIN CACHED loads: buffer `it` address is fresh for this XCD's L2
      // (or holds only same-XCD write-through lines) -> always coherent.
      const _Float16* a0p = hr + (m * 32 + lane16) * 2048 + kc * 256 + quad * 8;
      const _Float16* a1p = a0p + 16 * 2048;
      v8h A0[8], A1[8];
#pragma unroll
      for (int kk = 0; kk < 8; ++kk) A0[kk] = *(const v8h*)(a0p + kk * 32);
#pragma unroll
      for (int kk = 0; kk < 8; ++kk) A1[kk] = *(const v8h*)(a1p + kk * 32);
#pragma unroll
      for (int kk = 0; kk < 8; ++kk) {
        a00 = __builtin_amdgcn_mfma_f32_16x16x32_f16(A0[kk], breg0[kk], a00, 0, 0, 0);
        a10 = __builtin_amdgcn_mfma_f32_16x16x32_f16(A0[kk], breg1[kk], a10, 0, 0, 0);
      }
#pragma unroll
      for (int kk = 0; kk < 8; ++kk) {
        a01 = __builtin_amdgcn_mfma_f32_16x16x32_f16(A1[kk], breg0[kk], a01, 0, 0, 0);
        a11 = __builtin_amdgcn_mfma_f32_16x16x32_f16(A1[kk], breg1[kk], a11, 0, 0, 0);
      }
    }

    // C-tiles -> LDS, swizzled (see header). a00: rq=quad cb0; a01: rq=4+quad
    // cb0; a10/a11: cb1 (col ^16). Banks: 2-way max on writes.
#pragma unroll
    for (int r = 0; r < 4; ++r) {
      float* zp = &zs[((w * 4 + r) * 8 + quad) * 32];
      zp[cswz] = a00[r];
      zp[128 + cswz] = a01[r];
      zp[cswz ^ 16] = a10[r];
      zp[128 + (cswz ^ 16)] = a11[r];
    }
    __syncthreads();

    // owner reduction + cell update (vector b128 reads, gates contiguous)
    const bool do0 = (w < 4) && (it < 512);
    const bool do1 = (w >= 4 && w < 8) && (it >= 1);
    if (do0 || do1) {
      v4f z;
      if (do0) {
        z[0] = (float)tvh[0]; z[1] = (float)tvh[1];
        z[2] = (float)tvh[2]; z[3] = (float)tvh[3];
#pragma unroll
        for (int wv = 0; wv < 4; ++wv)
          z += *(const v4f*)&zs[((wv * 4 + rr) * 8 + rqo) * 32 + rcol];
      } else {
        z = bias4;
#pragma unroll
        for (int wv = 4; wv < 12; ++wv)
          z += *(const v4f*)&zs[((wv * 4 + rr) * 8 + rqo) * 32 + rcol];
      }
      const float ig = sigf(z[0]), fg = sigf(z[1]);
      const float gg = tanhfast(z[2]), og = sigf(z[3]);
      cst = fg * cst + ig * gg;
      const float hv = og * tanhfast(cst);

      // pack 8 unit-lanes (same b) -> two 8-B stores (lanes oj==0, oj==4)
      const unsigned hu =
          (unsigned)__builtin_bit_cast(unsigned short, (_Float16)hv);
      const unsigned p1 = (unsigned)__shfl_xor((int)hu, 1, 64);
      const unsigned lo = (oj & 1) ? ((p1 & 0xffffu) | (hu << 16))
                                   : ((hu & 0xffffu) | (p1 << 16));
      const unsigned p2 = (unsigned)__shfl_xor((int)lo, 2, 64);
      if ((oj & 3) == 0) {
        const u64t val = (u64t)lo | ((u64t)p2 << 32);
        if (do0) {
          __hip_atomic_store((u64t*)(hw + obg * 2048 + cg * 8 + oj), val,
                             __ATOMIC_RELAXED, __HIP_MEMORY_SCOPE_AGENT);
        } else {
          __hip_atomic_store((u64t*)(hw + obg * 2048 + 1024 + cg * 8 + oj),
                             val, __ATOMIC_RELAXED, __HIP_MEMORY_SCOPE_AGENT);
        }
      }
    }

    // prefetch next step's xin0 gather (tableV constant, L1-hot: no invs)
    if (w < 4 && it + 1 < 512) {
      const int xv = x[obg * 512 + it + 1];
#pragma unroll
      for (int g = 0; g < 4; ++g)
        tvh[g] = tableV[xv * 4096 + cg * 32 + ocb * 16 + g * 4 + ojj];
    }

    if (it < 512) {
      // ---- flat m-split barrier: one add, one poll stage, no leaders ----
      asm volatile("s_waitcnt vmcnt(0)" ::: "memory");  // h stores at L3
      __syncthreads();
      if (tid == 0) {
        atomicAdd(&bar[(m * 8 + gq) * 16], 1u);         // fire-and-forget
        const unsigned tgt = 16u * (unsigned)(it + 1);
        for (;;) {
          unsigned v[8];
#pragma unroll
          for (int g = 0; g < 8; ++g)
            v[g] = __hip_atomic_load(&bar[(m * 8 + g) * 16], __ATOMIC_RELAXED,
                                     __HIP_MEMORY_SCOPE_AGENT);
          unsigned mn = v[0];
#pragma unroll
          for (int g = 1; g < 8; ++g) mn = (v[g] < mn) ? v[g] : mn;
          if (mn >= tgt) break;
          __builtin_amdgcn_s_sleep(1);
        }
      }
      __syncthreads();
      // keep the fresh-buffer plain loads from being hoisted above release
      asm volatile("" ::: "memory");
    }
  }
}

// ---------------------------------------------------------------- FC ----
__global__ __launch_bounds__(256, 2) void fc_kernel(
    const _Float16* __restrict__ hseq, const _Float16* __restrict__ fcwT,
    const float* __restrict__ fc_b, float* __restrict__ out) {
  __shared__ float hl[16][1024];      // 64 KB
  const int tid = threadIdx.x;
  const int t = blockIdx.x >> 2, bs = blockIdx.x & 3;
  const int v = tid & 127, hh = tid >> 7;

  // h2[t][b][u] lives at hseq buffer t+2, row b, halfs 1024..2047
  const h2v* hp = (const h2v*)hseq;
  const size_t base = (size_t)(t + 2) * 65536 + 512;
  for (int idx = tid; idx < 8192; idx += 256) {
    const int bl = idx >> 9, kp = idx & 511;
    const h2v pr = hp[base + (size_t)((bs * 16 + bl)) * 1024 + kp];
    hl[bl][2 * kp] = (float)pr.x;
    hl[bl][2 * kp + 1] = (float)pr.y;
  }
  __syncthreads();

  float acc[8];
#pragma unroll
  for (int i = 0; i < 8; ++i) acc[i] = 0.0f;
  const int bl0 = hh * 8;
#pragma unroll 1
  for (int k4 = 0; k4 < 256; ++k4) {
    const int k = k4 * 4;
    const float w0 = (float)fcwT[(k + 0) * 128 + v];
    const float w1 = (float)fcwT[(k + 1) * 128 + v];
    const float w2 = (float)fcwT[(k + 2) * 128 + v];
    const float w3 = (float)fcwT[(k + 3) * 128 + v];
#pragma unroll
    for (int i = 0; i < 8; ++i) {
      const float4 hv = *(const float4*)&hl[bl0 + i][k];
      acc[i] += hv.x * w0 + hv.y * w1 + hv.z * w2 + hv.w * w3;
    }
  }
  const float bias = fc_b[v];
#pragma unroll
  for (int i = 0; i < 8; ++i) {
    const int bb = bs * 16 + bl0 + i;
    out[(bb * 512 + t) * 128 + v] = acc[i] + bias;
  }
}

// ------------------------------------------------------------- launch ----
extern "C" void kernel_launch(void* const* d_in, const int* in_sizes, int n_in,
                              void* d_out, int out_size, void* d_ws,
                              size_t ws_size, hipStream_t stream) {
  const int* x = (const int*)d_in[0];
  const float* emb = (const float*)d_in[1];
  const float* w_ih0 = (const float*)d_in[2];
  const float* w_hh0 = (const float*)d_in[3];
  const float* b_ih0 = (const float*)d_in[4];
  const float* b_hh0 = (const float*)d_in[5];
  const float* w_ih1 = (const float*)d_in[6];
  const float* w_hh1 = (const float*)d_in[7];
  const float* b_ih1 = (const float*)d_in[8];
  const float* b_hh1 = (const float*)d_in[9];
  const float* fc_w = (const float*)d_in[10];
  const float* fc_b = (const float*)d_in[11];
  float* out = (float*)d_out;

  char* ws = (char*)d_ws;
  _Float16* tableV = (_Float16*)(ws);
  _Float16* fcwT = (_Float16*)(ws + 1048576);
  unsigned* bar = (unsigned*)(ws + 1310720);
  _Float16* hseq = (_Float16*)(ws + 1376256);   // 514 x 262144 B
  unsigned* zb = (unsigned*)(ws + 1376256);     // zero buffers 0,1

  prep_kernel<<<2593, 256, 0, stream>>>(emb, w_ih0, b_ih0, b_hh0, fc_w,
                                        tableV, fcwT, zb, bar);

  const _Float16* tableVc = tableV;
  _Float16* hseqa = hseq;
  unsigned* bara = bar;
  void* args[] = {(void*)&x,     (void*)&tableVc, (void*)&w_hh0,
                  (void*)&w_ih1, (void*)&w_hh1,   (void*)&b_ih1,
                  (void*)&b_hh1, (void*)&hseqa,   (void*)&bara};
  hipLaunchCooperativeKernel(lstm_mfma, dim3(256), dim3(768), args, 0, stream);

  fc_kernel<<<2048, 256, 0, stream>>>(hseq, fcwT, fc_b, out);
}